// Round 6
// baseline (102.144 us; speedup 1.0000x reference)
//
#include <hip/hip_runtime.h>
#include <math.h>

// Problem constants (reference: N=250000, D=16, L=6, K=64, gamma=0.1)
#define NPOINTS 250000
#define LL 6
#define DD 16
#define KK 64

// R17 (resubmit; R5 bench was an infra failure, not a kernel verdict):
// wave-independent structure. Each wave owns 16 points and computes ALL
// 6 layers (B-fragments loop-invariant in registers). No barriers, no smc,
// no epilogue phase — the layer recurrence overlaps the next layer's MFMA.
// R0-R4 evidence: kernel pinned at ~42us while occupancy 23%->50% => stall
// was correlated across the 6-wave gang (lockstep LDS->MFMA + barriers).
#define TPB 256
#define WAVES_PER_BLOCK (TPB / 64)
#define PTS_PER_WAVE 16
#define PTS_PER_BLOCK (WAVES_PER_BLOCK * PTS_PER_WAVE)   // 64

// LDS: per-wave x staging only: 16 points * 80 B (32 hi + 32 lo + 16 pad)
#define LDS_BYTES (WAVES_PER_BLOCK * PTS_PER_WAVE * 80)  // 5120

// d_ws layout (bytes):
//  WS_MU: column (l*64+k) as 64 B = 32 B bf16-hi + 32 B bf16-lo, pre-scaled -1/2
//  WS_AV: av[l*64+k] = C_AA*alpha - W0
//  WS_WV: exp(-ws^2) per layer
#define WS_MU 0
#define WS_AV 24576
#define WS_WV 26112

typedef __attribute__((ext_vector_type(8))) short bf16x8;
typedef __attribute__((ext_vector_type(4))) float f32x4;
typedef __attribute__((ext_vector_type(2))) float f32x2;

#if __has_builtin(__builtin_amdgcn_exp2f)
#define EXP2F(x) __builtin_amdgcn_exp2f(x)
#else
#define EXP2F(x) exp2f(x)
#endif
#if __has_builtin(__builtin_amdgcn_logf)
#define LOG2F(x) __builtin_amdgcn_logf(x)
#else
#define LOG2F(x) log2f(x)
#endif

#define C_AA   (-14.426950408889634f)   // -10 * log2(e)
#define C_GLN2 (0.06931471805599453f)   // gamma * ln(2)

// Fused distance->log2 term: with mu pre-scaled by -1/2, MFMA emits x' = -ip/2
// and t2 = (aa - w0) + x'*Vt(x').  Vt = degree-5 poly (error budget: |err(F)|
// <= ~2.6e-4).  Estrin evaluation.
#define W0  17.797117f
#define VT0 (-45.300328f)
#define VT1 (-28.559404f)
#define VT2 (-27.844414f)
#define VT3 (-30.475230f)
#define VT4 (-36.246253f)
#define VT5 (-27.207285f)

__device__ __forceinline__ f32x2 s2(float v) { f32x2 r; r.x = v; r.y = v; return r; }

__device__ __forceinline__ ushort bf16_rne(float f) {
  unsigned u = __float_as_uint(f);
  unsigned r = u + 0x7FFFu + ((u >> 16) & 1u);
  return (ushort)(r >> 16);
}

// packed pair: exp2( (aa-w0) + xp*Vt(xp) ), xp = -ip/2 from MFMA.  Estrin:
// Vt = P01 + xp^2*(P23 + xp^2*P45), Pij = VTi + VTj*xp.
__device__ __forceinline__ f32x2 term2(f32x2 xp, f32x2 aaw) {
  f32x2 x2  = xp * xp;
  f32x2 p01 = __builtin_elementwise_fma(s2(VT1), xp, s2(VT0));
  f32x2 p23 = __builtin_elementwise_fma(s2(VT3), xp, s2(VT2));
  f32x2 p45 = __builtin_elementwise_fma(s2(VT5), xp, s2(VT4));
  f32x2 qq  = __builtin_elementwise_fma(x2, p45, p23);
  f32x2 V   = __builtin_elementwise_fma(x2, qq, p01);
  f32x2 t2  = __builtin_elementwise_fma(xp, V, aaw);
  f32x2 e; e.x = EXP2F(t2.x); e.y = EXP2F(t2.y);
  return e;
}

// ---- prep kernel: 1 block, 384 threads; thread t = (layer l, comp k) ----
__global__ __launch_bounds__(384) void
prep_kernel(const float* __restrict__ mus,    // [L, D, K]
            const float* __restrict__ alphas, // [L, K]
            const float* __restrict__ wsv,    // [L]
            char* __restrict__ ws) {
  const int t = threadIdx.x;          // 0..383 == l*64+k
  const float* colp = mus + (t >> 6) * (DD * KK) + (t & 63);
  float v[DD];
  float ss = 0.0f;
#pragma unroll
  for (int d = 0; d < DD; ++d) { v[d] = colp[d * KK]; ss = fmaf(v[d], v[d], ss); }
  float inv = -0.5f / sqrtf(ss);      // normalize AND scale by -1/2 (exact scale)
  unsigned hw[8], lw[8];
#pragma unroll
  for (int i = 0; i < 8; ++i) {
    float a0 = v[2 * i] * inv;
    float a1 = v[2 * i + 1] * inv;
    ushort h0 = bf16_rne(a0), h1 = bf16_rne(a1);
    float hf0 = __uint_as_float((unsigned)h0 << 16);
    float hf1 = __uint_as_float((unsigned)h1 << 16);
    ushort l0 = bf16_rne(a0 - hf0), l1 = bf16_rne(a1 - hf1);
    hw[i] = (unsigned)h0 | ((unsigned)h1 << 16);
    lw[i] = (unsigned)l0 | ((unsigned)l1 << 16);
  }
  uint4* colq = (uint4*)(ws + WS_MU + t * 64);
  colq[0] = make_uint4(hw[0], hw[1], hw[2], hw[3]);
  colq[1] = make_uint4(hw[4], hw[5], hw[6], hw[7]);
  colq[2] = make_uint4(lw[0], lw[1], lw[2], lw[3]);
  colq[3] = make_uint4(lw[4], lw[5], lw[6], lw[7]);
  ((float*)(ws + WS_AV))[t] = fmaf(C_AA, alphas[t], -W0);
  if (t < LL) { float x = wsv[t]; ((float*)(ws + WS_WV))[t] = expf(-x * x); }
}

__global__ __launch_bounds__(TPB, 4) void
multiinf_kernel(const float* __restrict__ xs,
                const char* __restrict__ ws,
                float* __restrict__ out) {
  __shared__ __align__(16) char smem[LDS_BYTES];

  const int tid = threadIdx.x;
  const int wid = tid >> 6;          // wave in block
  const int lane = tid & 63;
  const int c = lane & 15;           // MFMA col: point-in-tile (comp idx for A read)
  const int q = lane >> 4;           // quad
  const int h = q & 1;               // dim half for B (x) reads
  const int pt0 = blockIdx.x * PTS_PER_BLOCK + wid * PTS_PER_WAVE;
  char* sx = smem + wid * (PTS_PER_WAVE * 80);

  // ---- Stage this wave's 16 points: lane (c,q) loads point c, dims 4q..4q+3,
  //      packs bf16 hi/lo, writes its 2x8B. Same-wave LDS dep only (no barrier).
  {
    int gidx = pt0 + c;
    float4 a = make_float4(0.0f, 0.0f, 0.0f, 0.0f);
    if (gidx < NPOINTS) a = ((const float4*)(xs + (size_t)gidx * DD))[q];
    ushort h0 = bf16_rne(a.x), h1 = bf16_rne(a.y);
    ushort h2 = bf16_rne(a.z), h3 = bf16_rne(a.w);
    float hf0 = __uint_as_float((unsigned)h0 << 16);
    float hf1 = __uint_as_float((unsigned)h1 << 16);
    float hf2 = __uint_as_float((unsigned)h2 << 16);
    float hf3 = __uint_as_float((unsigned)h3 << 16);
    ushort l0 = bf16_rne(a.x - hf0), l1 = bf16_rne(a.y - hf1);
    ushort l2 = bf16_rne(a.z - hf2), l3 = bf16_rne(a.w - hf3);
    uint2 hwv, lwv;
    hwv.x = (unsigned)h0 | ((unsigned)h1 << 16);
    hwv.y = (unsigned)h2 | ((unsigned)h3 << 16);
    lwv.x = (unsigned)l0 | ((unsigned)l1 << 16);
    lwv.y = (unsigned)l2 | ((unsigned)l3 << 16);
    *(uint2*)(sx + c * 80 + q * 8) = hwv;        // hi words 2q,2q+1
    *(uint2*)(sx + c * 80 + 32 + q * 8) = lwv;   // lo words 2q,2q+1
  }

  // B fragments: LOOP-INVARIANT across all 6 layers (the R17 point).
  // Compiler orders the ds_read after the ds_writes via lgkmcnt (same wave).
  bf16x8 Bh = *(const bf16x8*)(sx + c * 80 + h * 16);
  bf16x8 Bl = *(const bf16x8*)(sx + c * 80 + 32 + h * 16);

  const float* swv = (const float*)(ws + WS_WV);
  const f32x4 zero4 = {0.0f, 0.0f, 0.0f, 0.0f};
  float F = 0.0f;

#pragma unroll 2
  for (int l = 0; l < LL; ++l) {
    // per-layer mu fragments + constants (ws is L1/L2-hot, 24.5 KB total)
    bf16x8 Am[4];
    f32x2 aaL[4], aaH[4];
#pragma unroll
    for (int cb = 0; cb < 4; ++cb) {
      Am[cb] = *(const bf16x8*)(ws + WS_MU + (l * 64 + cb * 16 + c) * 64 + q * 16);
      f32x4 a4 = *(const f32x4*)(ws + WS_AV + (l * 64 + cb * 16 + q * 4) * 4);
      aaL[cb].x = a4.x; aaL[cb].y = a4.y;
      aaH[cb].x = a4.z; aaH[cb].y = a4.w;
    }
    f32x2 S01 = s2(0.0f), S23 = s2(0.0f);
#pragma unroll
    for (int cb = 0; cb < 4; ++cb) {
      f32x4 acc = __builtin_amdgcn_mfma_f32_16x16x32_bf16(Am[cb], Bh, zero4, 0, 0, 0);
      acc = __builtin_amdgcn_mfma_f32_16x16x32_bf16(Am[cb], Bl, acc, 0, 0, 0);
      f32x2 a01; a01.x = acc[0]; a01.y = acc[1];
      f32x2 a23; a23.x = acc[2]; a23.y = acc[3];
      S01 += term2(a01, aaL[cb]);
      S23 += term2(a23, aaH[cb]);
    }
    f32x2 Sf = S01 + S23;
    float St = Sf.x + Sf.y;
    St += __shfl_xor(St, 16, 64);
    St += __shfl_xor(St, 32, 64);   // all lanes now hold sum over 64 comps
    // layer recurrence, branchless on all lanes (x4 redundant per point)
    float wvl = swv[l];
    float mc = C_GLN2 * LOG2F(St);  // gamma*ln(S)
    F = fmaf(wvl, fmaxf(F, 0.0f), (1.0f - wvl) * mc);
  }

  // ---- smooth-min + store: lanes 0..15 own points pt0+c ----
  if (lane < 16) {
    int idx = pt0 + c;
    if (idx < NPOINTS) {
      float e = EXP2F(F * C_AA);              // exp(-F/0.1)
      out[idx] = C_GLN2 * LOG2F(1.0f + e);    // 0.1 * ln(1 + e)
    }
  }
}

extern "C" void kernel_launch(void* const* d_in, const int* in_sizes, int n_in,
                              void* d_out, int out_size, void* d_ws, size_t ws_size,
                              hipStream_t stream) {
  const float* xs = (const float*)d_in[0];     // [N, D]
  const float* mus = (const float*)d_in[1];    // [L, D, K]
  const float* alphas = (const float*)d_in[2]; // [L, K]
  const float* wsv = (const float*)d_in[3];    // [L]
  float* out = (float*)d_out;
  char* ws = (char*)d_ws;
  (void)ws_size;

  prep_kernel<<<1, 384, 0, stream>>>(mus, alphas, wsv, ws);
  const int blocks = (NPOINTS + PTS_PER_BLOCK - 1) / PTS_PER_BLOCK;  // 3907
  multiinf_kernel<<<blocks, TPB, 0, stream>>>(xs, ws, out);
}

// Round 7
// 94.821 us; speedup vs baseline: 1.0772x; 1.0772x over previous
//
#include <hip/hip_runtime.h>
#include <math.h>

// Problem constants (reference: N=250000, D=16, L=6, K=64, gamma=0.1)
#define NPOINTS 250000
#define LL 6
#define DD 16
#define KK 64

// R18: 2 B-tiles (32 points) per wave. R6 proved the stall is per-wave
// dependency latency (44us invariant across occupancy 23->53%, barriers 3->0,
// waves decoupled; VALUBusy pinned 43%). Two independent MFMA->poly->exp->
// reduce chains per layer fill each other's latency; Am/aa loads, log, and
// the F-recurrence amortize over 2x points.
#define TPB 256
#define WAVES_PER_BLOCK (TPB / 64)
#define PTS_PER_WAVE 32
#define PTS_PER_BLOCK (WAVES_PER_BLOCK * PTS_PER_WAVE)   // 128

// LDS: per-wave x staging: 32 points * 80 B (32 hi + 32 lo + 16 pad)
#define LDS_BYTES (WAVES_PER_BLOCK * PTS_PER_WAVE * 80)  // 10240

// d_ws layout (bytes):
//  WS_MU: column (l*64+k) as 64 B = 32 B bf16-hi + 32 B bf16-lo, pre-scaled -1/2
//  WS_AV: av[l*64+k] = C_AA*alpha - W0
//  WS_WV: exp(-ws^2) per layer
#define WS_MU 0
#define WS_AV 24576
#define WS_WV 26112

typedef __attribute__((ext_vector_type(8))) short bf16x8;
typedef __attribute__((ext_vector_type(4))) float f32x4;
typedef __attribute__((ext_vector_type(2))) float f32x2;

#if __has_builtin(__builtin_amdgcn_exp2f)
#define EXP2F(x) __builtin_amdgcn_exp2f(x)
#else
#define EXP2F(x) exp2f(x)
#endif
#if __has_builtin(__builtin_amdgcn_logf)
#define LOG2F(x) __builtin_amdgcn_logf(x)
#else
#define LOG2F(x) log2f(x)
#endif

#define C_AA   (-14.426950408889634f)   // -10 * log2(e)
#define C_GLN2 (0.06931471805599453f)   // gamma * ln(2)

// Fused distance->log2 term: with mu pre-scaled by -1/2, MFMA emits x' = -ip/2
// and t2 = (aa - w0) + x'*Vt(x').  Vt = degree-5 poly (error budget: |err(F)|
// <= ~2.6e-4).  Estrin evaluation.
#define W0  17.797117f
#define VT0 (-45.300328f)
#define VT1 (-28.559404f)
#define VT2 (-27.844414f)
#define VT3 (-30.475230f)
#define VT4 (-36.246253f)
#define VT5 (-27.207285f)

__device__ __forceinline__ f32x2 s2(float v) { f32x2 r; r.x = v; r.y = v; return r; }

__device__ __forceinline__ ushort bf16_rne(float f) {
  unsigned u = __float_as_uint(f);
  unsigned r = u + 0x7FFFu + ((u >> 16) & 1u);
  return (ushort)(r >> 16);
}

// packed pair: exp2( (aa-w0) + xp*Vt(xp) ), xp = -ip/2 from MFMA.  Estrin:
// Vt = P01 + xp^2*(P23 + xp^2*P45), Pij = VTi + VTj*xp.
__device__ __forceinline__ f32x2 term2(f32x2 xp, f32x2 aaw) {
  f32x2 x2  = xp * xp;
  f32x2 p01 = __builtin_elementwise_fma(s2(VT1), xp, s2(VT0));
  f32x2 p23 = __builtin_elementwise_fma(s2(VT3), xp, s2(VT2));
  f32x2 p45 = __builtin_elementwise_fma(s2(VT5), xp, s2(VT4));
  f32x2 qq  = __builtin_elementwise_fma(x2, p45, p23);
  f32x2 V   = __builtin_elementwise_fma(x2, qq, p01);
  f32x2 t2  = __builtin_elementwise_fma(xp, V, aaw);
  f32x2 e; e.x = EXP2F(t2.x); e.y = EXP2F(t2.y);
  return e;
}

// pack one float4 (dims 4q..4q+3) of a point into bf16 hi/lo at dst
__device__ __forceinline__ void pack_pt(char* dst, float4 a, int q) {
  ushort h0 = bf16_rne(a.x), h1 = bf16_rne(a.y);
  ushort h2 = bf16_rne(a.z), h3 = bf16_rne(a.w);
  float hf0 = __uint_as_float((unsigned)h0 << 16);
  float hf1 = __uint_as_float((unsigned)h1 << 16);
  float hf2 = __uint_as_float((unsigned)h2 << 16);
  float hf3 = __uint_as_float((unsigned)h3 << 16);
  ushort l0 = bf16_rne(a.x - hf0), l1 = bf16_rne(a.y - hf1);
  ushort l2 = bf16_rne(a.z - hf2), l3 = bf16_rne(a.w - hf3);
  uint2 hwv, lwv;
  hwv.x = (unsigned)h0 | ((unsigned)h1 << 16);
  hwv.y = (unsigned)h2 | ((unsigned)h3 << 16);
  lwv.x = (unsigned)l0 | ((unsigned)l1 << 16);
  lwv.y = (unsigned)l2 | ((unsigned)l3 << 16);
  *(uint2*)(dst + q * 8) = hwv;        // hi words 2q,2q+1
  *(uint2*)(dst + 32 + q * 8) = lwv;   // lo words 2q,2q+1
}

// ---- prep kernel: 1 block, 384 threads; thread t = (layer l, comp k) ----
__global__ __launch_bounds__(384) void
prep_kernel(const float* __restrict__ mus,    // [L, D, K]
            const float* __restrict__ alphas, // [L, K]
            const float* __restrict__ wsv,    // [L]
            char* __restrict__ ws) {
  const int t = threadIdx.x;          // 0..383 == l*64+k
  const float* colp = mus + (t >> 6) * (DD * KK) + (t & 63);
  float v[DD];
  float ss = 0.0f;
#pragma unroll
  for (int d = 0; d < DD; ++d) { v[d] = colp[d * KK]; ss = fmaf(v[d], v[d], ss); }
  float inv = -0.5f / sqrtf(ss);      // normalize AND scale by -1/2 (exact scale)
  unsigned hw[8], lw[8];
#pragma unroll
  for (int i = 0; i < 8; ++i) {
    float a0 = v[2 * i] * inv;
    float a1 = v[2 * i + 1] * inv;
    ushort h0 = bf16_rne(a0), h1 = bf16_rne(a1);
    float hf0 = __uint_as_float((unsigned)h0 << 16);
    float hf1 = __uint_as_float((unsigned)h1 << 16);
    ushort l0 = bf16_rne(a0 - hf0), l1 = bf16_rne(a1 - hf1);
    hw[i] = (unsigned)h0 | ((unsigned)h1 << 16);
    lw[i] = (unsigned)l0 | ((unsigned)l1 << 16);
  }
  uint4* colq = (uint4*)(ws + WS_MU + t * 64);
  colq[0] = make_uint4(hw[0], hw[1], hw[2], hw[3]);
  colq[1] = make_uint4(hw[4], hw[5], hw[6], hw[7]);
  colq[2] = make_uint4(lw[0], lw[1], lw[2], lw[3]);
  colq[3] = make_uint4(lw[4], lw[5], lw[6], lw[7]);
  ((float*)(ws + WS_AV))[t] = fmaf(C_AA, alphas[t], -W0);
  if (t < LL) { float x = wsv[t]; ((float*)(ws + WS_WV))[t] = expf(-x * x); }
}

__global__ __launch_bounds__(TPB, 4) void
multiinf_kernel(const float* __restrict__ xs,
                const char* __restrict__ ws,
                float* __restrict__ out) {
  __shared__ __align__(16) char smem[LDS_BYTES];

  const int tid = threadIdx.x;
  const int wid = tid >> 6;          // wave in block
  const int lane = tid & 63;
  const int c = lane & 15;           // MFMA col: point-in-tile (comp idx for A read)
  const int q = lane >> 4;           // quad
  const int h = q & 1;               // dim half for B (x) reads
  const int pt0 = blockIdx.x * PTS_PER_BLOCK + wid * PTS_PER_WAVE;
  char* sx = smem + wid * (PTS_PER_WAVE * 80);

  // ---- Stage this wave's 32 points: lane (c,q) loads points c and c+16,
  //      dims 4q..4q+3 each, packs bf16 hi/lo. Same-wave LDS dep only.
  {
    int p0 = pt0 + c;
    int p1 = pt0 + 16 + c;
    float4 a0 = make_float4(0.0f, 0.0f, 0.0f, 0.0f);
    float4 a1 = a0;
    if (p0 < NPOINTS) a0 = ((const float4*)(xs + (size_t)p0 * DD))[q];
    if (p1 < NPOINTS) a1 = ((const float4*)(xs + (size_t)p1 * DD))[q];
    pack_pt(sx + c * 80, a0, q);
    pack_pt(sx + (16 + c) * 80, a1, q);
  }

  // B fragments: LOOP-INVARIANT across all 6 layers; two tiles per wave.
  bf16x8 Bh0 = *(const bf16x8*)(sx + c * 80 + h * 16);
  bf16x8 Bl0 = *(const bf16x8*)(sx + c * 80 + 32 + h * 16);
  bf16x8 Bh1 = *(const bf16x8*)(sx + (16 + c) * 80 + h * 16);
  bf16x8 Bl1 = *(const bf16x8*)(sx + (16 + c) * 80 + 32 + h * 16);

  const float* swv = (const float*)(ws + WS_WV);
  const f32x4 zero4 = {0.0f, 0.0f, 0.0f, 0.0f};
  float F0 = 0.0f, F1 = 0.0f;

#pragma unroll 2
  for (int l = 0; l < LL; ++l) {
    // per-layer mu fragments + constants (ws is L1/L2-hot, 24.5 KB total)
    bf16x8 Am[4];
    f32x2 aaL[4], aaH[4];
#pragma unroll
    for (int cb = 0; cb < 4; ++cb) {
      Am[cb] = *(const bf16x8*)(ws + WS_MU + (l * 64 + cb * 16 + c) * 64 + q * 16);
      f32x4 a4 = *(const f32x4*)(ws + WS_AV + (l * 64 + cb * 16 + q * 4) * 4);
      aaL[cb].x = a4.x; aaL[cb].y = a4.y;
      aaH[cb].x = a4.z; aaH[cb].y = a4.w;
    }
    f32x2 S01a = s2(0.0f), S23a = s2(0.0f);
    f32x2 S01b = s2(0.0f), S23b = s2(0.0f);
#pragma unroll
    for (int cb = 0; cb < 4; ++cb) {
      f32x4 accA = __builtin_amdgcn_mfma_f32_16x16x32_bf16(Am[cb], Bh0, zero4, 0, 0, 0);
      accA = __builtin_amdgcn_mfma_f32_16x16x32_bf16(Am[cb], Bl0, accA, 0, 0, 0);
      f32x4 accB = __builtin_amdgcn_mfma_f32_16x16x32_bf16(Am[cb], Bh1, zero4, 0, 0, 0);
      accB = __builtin_amdgcn_mfma_f32_16x16x32_bf16(Am[cb], Bl1, accB, 0, 0, 0);
      f32x2 a01, a23, b01, b23;
      a01.x = accA[0]; a01.y = accA[1]; a23.x = accA[2]; a23.y = accA[3];
      b01.x = accB[0]; b01.y = accB[1]; b23.x = accB[2]; b23.y = accB[3];
      S01a += term2(a01, aaL[cb]);
      S23a += term2(a23, aaH[cb]);
      S01b += term2(b01, aaL[cb]);
      S23b += term2(b23, aaH[cb]);
    }
    f32x2 Sfa = S01a + S23a;
    f32x2 Sfb = S01b + S23b;
    float St0 = Sfa.x + Sfa.y;
    float St1 = Sfb.x + Sfb.y;
    St0 += __shfl_xor(St0, 16, 64);
    St0 += __shfl_xor(St0, 32, 64);   // sum over 64 comps, tile 0
    St1 += __shfl_xor(St1, 16, 64);
    St1 += __shfl_xor(St1, 32, 64);   // sum over 64 comps, tile 1
    float wvl = swv[l];
    float mc0 = C_GLN2 * LOG2F(St0);  // gamma*ln(S)
    float mc1 = C_GLN2 * LOG2F(St1);
    F0 = fmaf(wvl, fmaxf(F0, 0.0f), (1.0f - wvl) * mc0);
    F1 = fmaf(wvl, fmaxf(F1, 0.0f), (1.0f - wvl) * mc1);
  }

  // ---- smooth-min + store: lanes 0..15 own tile0, lanes 16..31 own tile1 ----
  if (lane < 32) {
    float Fv = (lane < 16) ? F0 : F1;
    int idx = pt0 + (lane & 16) + c;
    if (idx < NPOINTS) {
      float e = EXP2F(Fv * C_AA);             // exp(-F/0.1)
      out[idx] = C_GLN2 * LOG2F(1.0f + e);    // 0.1 * ln(1 + e)
    }
  }
}

extern "C" void kernel_launch(void* const* d_in, const int* in_sizes, int n_in,
                              void* d_out, int out_size, void* d_ws, size_t ws_size,
                              hipStream_t stream) {
  const float* xs = (const float*)d_in[0];     // [N, D]
  const float* mus = (const float*)d_in[1];    // [L, D, K]
  const float* alphas = (const float*)d_in[2]; // [L, K]
  const float* wsv = (const float*)d_in[3];    // [L]
  float* out = (float*)d_out;
  char* ws = (char*)d_ws;
  (void)ws_size;

  prep_kernel<<<1, 384, 0, stream>>>(mus, alphas, wsv, ws);
  const int blocks = (NPOINTS + PTS_PER_BLOCK - 1) / PTS_PER_BLOCK;  // 1954
  multiinf_kernel<<<blocks, TPB, 0, stream>>>(xs, ws, out);
}